// Round 9
// baseline (992.009 us; speedup 1.0000x reference)
//
#include <hip/hip_runtime.h>
#include <hip/hip_bf16.h>

#define NBLK 64
#define BS   128
#define GSZ  8192   // NBLK * BS

// ---------- wave-uniform register fetch helpers (lane index must be uniform) ----------
__device__ __forceinline__ int rl32(int v, int sl) {
    return __builtin_amdgcn_readlane(v, sl);
}
__device__ __forceinline__ double rl64(double v, int sl) {
    union { double d; unsigned u[2]; } a; a.d = v;
    unsigned lo = (unsigned)__builtin_amdgcn_readlane((int)a.u[0], sl);
    unsigned hi = (unsigned)__builtin_amdgcn_readlane((int)a.u[1], sl);
    union { unsigned u[2]; double d; } r; r.u[0] = lo; r.u[1] = hi;
    return r.d;
}
// ARR/transfer key: monotone f64 -> u64, low 8 bits = column (np.argmin tie-break).
__device__ __forceinline__ unsigned long long pkeyc(double m, int col) {
    union { double d; unsigned long long u; } a; a.d = m;
    unsigned long long x = a.u;
    x = (x >> 63) ? ~x : (x | 0x8000000000000000ull);
    return (x & ~0xFFull) | (unsigned long long)(unsigned)col;
}
// Dijkstra key: value bits [63:16] | owner-row pj [15:8] | col [7:0]. The
// matching is static within a phase, so pj rides in the key — the winning
// column's owner, its dual (rl64), and the next row ds_read all issue right
// after the argmin with no dependent readlane. 16-bit truncation perturbs
// pop order only at 2^-37 relative; dual updates use exact f64 values.
__device__ __forceinline__ unsigned long long pkey16(double m, int pj, int col) {
    union { double d; unsigned long long u; } a; a.d = m;
    unsigned long long x = a.u;
    x = (x >> 63) ? ~x : (x | 0x8000000000000000ull);
    return (x & ~0xFFFFull) | ((unsigned long long)(unsigned)pj << 8)
                            | (unsigned long long)(unsigned)col;
}

// rocPRIM-style wave64 min via DPP: row_shr 1/2/4/8 then row_bcast 15/31.
__device__ __forceinline__ unsigned wave_min_u32_dpp(unsigned x) {
    x = min(x, (unsigned)__builtin_amdgcn_update_dpp((int)x, (int)x, 0x111, 0xf, 0xf, false)); // row_shr:1
    x = min(x, (unsigned)__builtin_amdgcn_update_dpp((int)x, (int)x, 0x112, 0xf, 0xf, false)); // row_shr:2
    x = min(x, (unsigned)__builtin_amdgcn_update_dpp((int)x, (int)x, 0x114, 0xf, 0xf, false)); // row_shr:4
    x = min(x, (unsigned)__builtin_amdgcn_update_dpp((int)x, (int)x, 0x118, 0xf, 0xf, false)); // row_shr:8
    x = min(x, (unsigned)__builtin_amdgcn_update_dpp((int)x, (int)x, 0x142, 0xa, 0xf, false)); // row_bcast:15
    x = min(x, (unsigned)__builtin_amdgcn_update_dpp((int)x, (int)x, 0x143, 0xc, 0xf, false)); // row_bcast:31
    return (unsigned)__builtin_amdgcn_readlane((int)x, 63);
}
// exact u64-key min across the wave.
__device__ __forceinline__ unsigned long long wave_min_key(unsigned long long k) {
    unsigned hi = (unsigned)(k >> 32);
    unsigned lo = (unsigned)k;
    unsigned mh = wave_min_u32_dpp(hi);
    unsigned long long msk = __ballot(hi == mh);
    unsigned lo_cand = (hi == mh) ? lo : 0xFFFFFFFFu;
    unsigned ml;
    if (__popcll(msk) == 1) {
        ml = (unsigned)__builtin_amdgcn_readlane((int)lo_cand, (int)__builtin_ctzll(msk));
    } else {
        ml = wave_min_u32_dpp(lo_cand);
    }
    return ((unsigned long long)mh << 32) | ml;
}

// ---------------------------------------------------------------------------
// Fused kernel (256 thr): sinkhorn (first 128 thr) -> { wave0: col-reduction
// seed + reduction transfer + ARR + register-JV Dijkstra (pj-in-key),
// waves1-3: zero-fill the 128x8192 stripe } -> scatter ones.
// ---------------------------------------------------------------------------
__global__ __launch_bounds__(256) void k_fused(const float* __restrict__ w,
                                               const float* __restrict__ scale_p,
                                               float* __restrict__ out) {
    __shared__ float M[BS][BS + 1];   // [128][129] f32: conflict-free rows+cols
    __shared__ int   rowasg[BS];
    float* Mf = &M[0][0];

    const int b = blockIdx.x;
    const int t = threadIdx.x;
    const float scale = *scale_p;

    // ---- sinkhorn: P = sinkhorn(softmax(clamp(w*scale,-1,1)/3)) ----
    if (t < BS) {
        for (int r = 0; r < BS; ++r) {
            float x = w[((size_t)b * BS + r) * BS + t] * scale;
            x = fminf(fmaxf(x, -1.0f), 1.0f);
            M[r][t] = x / 3.0f;
        }
    }
    __syncthreads();
    if (t < BS) {   // softmax along rows (thread t owns row t)
        float mx = M[t][0];
        for (int c = 1; c < BS; ++c) mx = fmaxf(mx, M[t][c]);
        float s = 0.0f;
        for (int c = 0; c < BS; ++c) { float e = expf(M[t][c] - mx); M[t][c] = e; s += e; }
        float rs = 1.0f / s;
        for (int c = 0; c < BS; ++c) M[t][c] *= rs;
    }
    __syncthreads();
    for (int it = 0; it < 5; ++it) {
        if (t < BS) {
            float s = 0.0f;
            for (int c = 0; c < BS; ++c) s += M[t][c];
            float rs = 1.0f / s;
            for (int c = 0; c < BS; ++c) M[t][c] *= rs;
        }
        __syncthreads();
        if (t < BS) {
            float s = 0.0f;
            for (int r = 0; r < BS; ++r) s += M[r][t];
            float rs = 1.0f / s;
            for (int r = 0; r < BS; ++r) M[r][t] *= rs;
        }
        __syncthreads();
    }

    int pA = 0, pB = 0;   // row (1-based) assigned to cols t+1 / t+65; 0 = free

    if (t >= 64) {
        // ---- waves1-3: zero the 128-row output stripe (hidden under LAP) ----
        const int l = t - 64;   // 0..191
        float4 z = make_float4(0.f, 0.f, 0.f, 0.f);
        float4* o4 = reinterpret_cast<float4*>(out + (size_t)b * BS * GSZ);
        for (int k = l; k < BS * GSZ / 4; k += 192) o4[k] = z;
    } else {
        // ---- wave0: exact LAP on cost = -P, all state in registers ----
        const int jAcol = t + 1, jBcol = t + 65;
        double uA = 0.0, uB = 0.0, vA, vB;

        // column reduction seed: v[j] = min_i cost = -(max_i P); greedy assign
        {
            float cmA = Mf[t];      int raA = 0;
            float cmB = Mf[t + 64]; int raB = 0;
            for (int r = 1; r < BS; ++r) {
                float xA = Mf[r * (BS + 1) + t];
                if (xA > cmA) { cmA = xA; raA = r; }
                float xB = Mf[r * (BS + 1) + t + 64];
                if (xB > cmB) { cmB = xB; raB = r; }
            }
            vA = -(double)cmA; vB = -(double)cmB;
            rowasg[t] = 0x7FFFFFFF; rowasg[t + 64] = 0x7FFFFFFF;
            __threadfence_block();
            atomicMin(&rowasg[raA], jAcol);
            atomicMin(&rowasg[raB], jBcol);
            __threadfence_block();
            pA = (rowasg[raA] == jAcol) ? raA + 1 : 0;
            pB = (rowasg[raB] == jBcol) ? raB + 1 : 0;
        }

        // unassigned-row masks (rows 1..64 in un0, 65..128 in un1)
        unsigned long long un0 = __ballot(rowasg[t]      == 0x7FFFFFFF);
        unsigned long long un1 = __ballot(rowasg[t + 64] == 0x7FFFFFFF);

        // ---- reduction transfer (lapjv step 2): for each assigned row r->jr:
        // mu = min_{j!=jr}(c[r][j] - v[j]); u_r := mu, v[jr] -= mu.
        // Per step: v only decreases (free rows stay feasible at u=0), the
        // matched edge stays tight, and columns are distinct across rows so
        // earlier updates are never clobbered. Moves all slack onto v so ARR
        // gets real second-min gaps (kills flat-matrix displacement churn).
        {
            const int asgA = rowasg[t];          // col of row t+1 (or 0x7FFFFFFF)
            const int asgB = rowasg[t + 64];
            unsigned long long as0 = ~un0, as1 = ~un1;
            while (as0 | as1) {
                int r;   // 0-based row
                if (as0) { r = __builtin_ctzll(as0); as0 &= as0 - 1; }
                else     { r = 64 + __builtin_ctzll(as1); as1 &= as1 - 1; }
                const int jr = rl32(r < 64 ? asgA : asgB, r & 63);
                double dA = -(double)Mf[r * (BS + 1) + t]      - vA;
                double dB = -(double)Mf[r * (BS + 1) + t + 64] - vB;
                unsigned long long kA = (jAcol == jr) ? ~0ull : pkeyc(dA, jAcol);
                unsigned long long kB = (jBcol == jr) ? ~0ull : pkeyc(dB, jBcol);
                unsigned long long km = wave_min_key(kA < kB ? kA : kB);
                const int  slm = ((int)(km & 0xFFull) - 1) & 63;
                const bool hm  = (int)(km & 0xFFull) > 64;
                double mu = rl64(hm ? dB : dA, slm);
                if (t == ((jr - 1) & 63)) {
                    if (jr > 64) { uB = mu; vB -= mu; }
                    else         { uA = mu; vA -= mu; }
                }
            }
        }

        // ---- ARR: augmenting row reduction (lapjv), with progress guard.
        // Keeps v non-increasing (free rows stay feasible at u=0); winners
        // assigned tight (u=u2, v[j1] -= u2-u1). Dijkstra finishes exactly.
        {
            int lastFree = 2 * BS;
            for (int steps = 0; (un0 | un1) && steps < 2048; ++steps) {
                int i;
                if (un0) i = __builtin_ctzll(un0) + 1;
                else     i = __builtin_ctzll(un1) + 65;

                double dA = -(double)Mf[(i - 1) * (BS + 1) + t]      - vA;
                double dB = -(double)Mf[(i - 1) * (BS + 1) + t + 64] - vB;
                unsigned long long kA = pkeyc(dA, jAcol), kB = pkeyc(dB, jBcol);

                unsigned long long k1 = wave_min_key(kA < kB ? kA : kB);
                const int  j1  = (int)(k1 & 0xFFull);
                const int  sl1 = (j1 - 1) & 63;
                const bool h1  = j1 > 64;
                double u1 = rl64(h1 ? dB : dA, sl1);

                unsigned long long kA2 = (jAcol == j1) ? ~0ull : kA;
                unsigned long long kB2 = (jBcol == j1) ? ~0ull : kB;
                unsigned long long k2 = wave_min_key(kA2 < kB2 ? kA2 : kB2);
                const int  sl2 = ((int)(k2 & 0xFFull) - 1) & 63;
                const bool h2  = (int)(k2 & 0xFFull) > 64;
                double u2 = rl64(h2 ? dB : dA, sl2);

                int i1 = rl32(h1 ? pB : pA, sl1);   // previous owner of j1 (0 = none)

                if (t == sl1) {
                    if (h1) { pB = i; uB = u2; if (u1 < u2) vB -= (u2 - u1); }
                    else    { pA = i; uA = u2; if (u1 < u2) vA -= (u2 - u1); }
                }
                if (i <= 64) un0 &= ~(1ull << (i - 1)); else un1 &= ~(1ull << (i - 65));
                if (i1 > 0) {
                    if (i1 <= 64) un0 |= 1ull << (i1 - 1); else un1 |= 1ull << (i1 - 65);
                }
                if ((steps & 127) == 127) {           // progress guard
                    int f = __popcll(un0) + __popcll(un1);
                    if (f >= lastFree) break;
                    lastFree = f;
                }
            }
        }

        // ---- single-source Dijkstra phases (R4-verified recursion, pj-in-key) ----
        while (un0 | un1) {
            int i;
            if (un0) { int r = __builtin_ctzll(un0); un0 &= un0 - 1; i = r + 1; }
            else     { int r = __builtin_ctzll(un1); un1 &= un1 - 1; i = r + 65; }

            bool usedA = false, usedB = false;
            double mA = 1e18, mB = 1e18, SUM = 0.0;   // stored m = true_minv + SUM
            unsigned long long keyA = ~0ull, keyB = ~0ull;
            int wayA = 0, wayB = 0;
            int i0 = i, j0 = 0;
            double ui0 = 0.0;                          // free row: u = 0

            for (int guard = 0; guard <= BS + 2; ++guard) {
                // scan row i0 against this lane's two columns
                float cAv = Mf[(i0 - 1) * (BS + 1) + t];
                float cBv = Mf[(i0 - 1) * (BS + 1) + t + 64];
                if (!usedA) {
                    double nd = (-(double)cAv - ui0 - vA) + SUM;
                    if (nd < mA) { mA = nd; wayA = j0; keyA = pkey16(nd, pA, jAcol); }
                }
                if (!usedB) {
                    double nd = (-(double)cBv - ui0 - vB) + SUM;
                    if (nd < mB) { mB = nd; wayB = j0; keyB = pkey16(nd, pB, jBcol); }
                }
                unsigned long long kw = wave_min_key(keyA < keyB ? keyA : keyB);
                if (kw == ~0ull) break;                  // safety: fail visibly
                const int  j1 = (int)(kw & 0xFFull);
                const int  pj = (int)((kw >> 8) & 0xFFull);
                const int  sl = (j1 - 1) & 63;
                const bool hb = j1 > 64;

                double m_win = rl64(hb ? mB : mA, sl);   // exact f64 min value
                double delta = m_win - SUM;
                SUM = m_win;
                if (usedA) { uA += delta; vA -= delta; }
                if (usedB) { uB += delta; vB -= delta; }

                j0 = j1;
                if (pj == 0) break;                      // free column: augment
                ui0 = rl64(hb ? uB : uA, sl);            // owner u (pre-mark)
                i0 = pj;
                if (t == sl) { if (hb) { usedB = true; keyB = ~0ull; }
                               else    { usedA = true; keyA = ~0ull; } }
            }

            // augment along way-chain; duals u travel with their rows
            int jc = j0;
            for (int guard = 0; guard <= BS + 2; ++guard) {
                const int  slc = (jc - 1) & 63;
                const bool hc  = jc > 64;
                int jp = rl32(hc ? wayB : wayA, slc);
                int nprow; double nu;
                if (jp == 0) { nprow = i; nu = SUM; }    // start row: u was 0
                else {
                    const int  slp = (jp - 1) & 63;
                    const bool hp  = jp > 64;
                    nprow = rl32(hp ? pB : pA, slp);
                    nu    = rl64(hp ? uB : uA, slp);
                }
                if (!hc) { if (t == slc) { pA = nprow; uA = nu; } }
                else     { if (t == slc) { pB = nprow; uB = nu; } }
                if (jp == 0) break;
                jc = jp;
            }
        }
    }

    __syncthreads();   // stripe fully zeroed, assignment final

    if (t < 64) {
        const size_t base = (size_t)b * BS;
        if (pA >= 1) out[(base + (size_t)(pA - 1)) * GSZ + base + t]      = 1.0f;
        if (pB >= 1) out[(base + (size_t)(pB - 1)) * GSZ + base + t + 64] = 1.0f;
    }
}

extern "C" void kernel_launch(void* const* d_in, const int* in_sizes, int n_in,
                              void* d_out, int out_size, void* d_ws, size_t ws_size,
                              hipStream_t stream) {
    const float* w     = (const float*)d_in[0];
    const float* scale = (const float*)d_in[1];
    float* out = (float*)d_out;
    k_fused<<<NBLK, 256, 0, stream>>>(w, scale, out);
}

// Round 10
// 748.611 us; speedup vs baseline: 1.3251x; 1.3251x over previous
//
#include <hip/hip_runtime.h>
#include <hip/hip_bf16.h>

#define NBLK 64
#define BS   128
#define GSZ  8192   // NBLK * BS

// ---------- wave-uniform register fetch helpers (lane index must be uniform) ----------
__device__ __forceinline__ int rl32(int v, int sl) {
    return __builtin_amdgcn_readlane(v, sl);
}
__device__ __forceinline__ double rl64(double v, int sl) {
    union { double d; unsigned u[2]; } a; a.d = v;
    unsigned lo = (unsigned)__builtin_amdgcn_readlane((int)a.u[0], sl);
    unsigned hi = (unsigned)__builtin_amdgcn_readlane((int)a.u[1], sl);
    union { unsigned u[2]; double d; } r; r.u[0] = lo; r.u[1] = hi;
    return r.d;
}
// ARR/transfer key: monotone f64 -> u64, low 8 bits = column (np.argmin tie-break).
__device__ __forceinline__ unsigned long long pkeyc(double m, int col) {
    union { double d; unsigned long long u; } a; a.d = m;
    unsigned long long x = a.u;
    x = (x >> 63) ? ~x : (x | 0x8000000000000000ull);
    return (x & ~0xFFull) | (unsigned long long)(unsigned)col;
}
// invert the monotone map on a key with low 8 bits (col) zeroed: value bits
// [63:8] -> f64, truncated toward -inf by < 2^-44 relative. Used consistently
// everywhere a value is extracted, so dual algebra stays self-consistent.
__device__ __forceinline__ double keyc_val(unsigned long long k) {
    unsigned long long x = k & ~0xFFull;
    x = (x & 0x8000000000000000ull) ? (x & 0x7FFFFFFFFFFFFFFFull) : ~x;
    union { unsigned long long u; double d; } r; r.u = x;
    return r.d;
}
// Dijkstra key: value bits [63:16] | owner-row pj [15:8] | col [7:0]. The
// matching is static within a phase, so pj rides in the key — the winning
// column's owner and the next row ds_read issue right after the argmin with
// no dependent readlane. 16-bit truncation perturbs pop order and (via
// key16_val) the duals by < 2^-36 relative — far below optimum margins.
__device__ __forceinline__ unsigned long long pkey16(double m, int pj, int col) {
    union { double d; unsigned long long u; } a; a.d = m;
    unsigned long long x = a.u;
    x = (x >> 63) ? ~x : (x | 0x8000000000000000ull);
    return (x & ~0xFFFFull) | ((unsigned long long)(unsigned)pj << 8)
                            | (unsigned long long)(unsigned)col;
}
// value extraction for pkey16 keys (local VALU, replaces a dependent rl64
// on the SUM critical path).
__device__ __forceinline__ double key16_val(unsigned long long k) {
    unsigned long long x = k & ~0xFFFFull;
    x = (x & 0x8000000000000000ull) ? (x & 0x7FFFFFFFFFFFFFFFull) : ~x;
    union { unsigned long long u; double d; } r; r.u = x;
    return r.d;
}

// rocPRIM-style wave64 min via DPP: row_shr 1/2/4/8 then row_bcast 15/31.
__device__ __forceinline__ unsigned wave_min_u32_dpp(unsigned x) {
    x = min(x, (unsigned)__builtin_amdgcn_update_dpp((int)x, (int)x, 0x111, 0xf, 0xf, false)); // row_shr:1
    x = min(x, (unsigned)__builtin_amdgcn_update_dpp((int)x, (int)x, 0x112, 0xf, 0xf, false)); // row_shr:2
    x = min(x, (unsigned)__builtin_amdgcn_update_dpp((int)x, (int)x, 0x114, 0xf, 0xf, false)); // row_shr:4
    x = min(x, (unsigned)__builtin_amdgcn_update_dpp((int)x, (int)x, 0x118, 0xf, 0xf, false)); // row_shr:8
    x = min(x, (unsigned)__builtin_amdgcn_update_dpp((int)x, (int)x, 0x142, 0xa, 0xf, false)); // row_bcast:15
    x = min(x, (unsigned)__builtin_amdgcn_update_dpp((int)x, (int)x, 0x143, 0xc, 0xf, false)); // row_bcast:31
    return (unsigned)__builtin_amdgcn_readlane((int)x, 63);
}
// exact u64-key min across the wave.
__device__ __forceinline__ unsigned long long wave_min_key(unsigned long long k) {
    unsigned hi = (unsigned)(k >> 32);
    unsigned lo = (unsigned)k;
    unsigned mh = wave_min_u32_dpp(hi);
    unsigned long long msk = __ballot(hi == mh);
    unsigned lo_cand = (hi == mh) ? lo : 0xFFFFFFFFu;
    unsigned ml;
    if (__popcll(msk) == 1) {
        ml = (unsigned)__builtin_amdgcn_readlane((int)lo_cand, (int)__builtin_ctzll(msk));
    } else {
        ml = wave_min_u32_dpp(lo_cand);
    }
    return ((unsigned long long)mh << 32) | ml;
}

// ---------------------------------------------------------------------------
// Fused kernel (256 thr): sinkhorn (first 128 thr) -> { wave0: col-reduction
// seed + sequential ARR-512 + register-JV Dijkstra (pj-in-key, key-valued),
// waves1-3: zero-fill the 128x8192 stripe } -> scatter ones.
// ---------------------------------------------------------------------------
__global__ __launch_bounds__(256) void k_fused(const float* __restrict__ w,
                                               const float* __restrict__ scale_p,
                                               float* __restrict__ out) {
    __shared__ float M[BS][BS + 1];   // [128][129] f32: conflict-free rows+cols
    __shared__ int   rowasg[BS];
    float* Mf = &M[0][0];

    const int b = blockIdx.x;
    const int t = threadIdx.x;
    const float scale = *scale_p;

    // ---- sinkhorn: P = sinkhorn(softmax(clamp(w*scale,-1,1)/3)) ----
    if (t < BS) {
        for (int r = 0; r < BS; ++r) {
            float x = w[((size_t)b * BS + r) * BS + t] * scale;
            x = fminf(fmaxf(x, -1.0f), 1.0f);
            M[r][t] = x / 3.0f;
        }
    }
    __syncthreads();
    if (t < BS) {   // softmax along rows (thread t owns row t)
        float mx = M[t][0];
        for (int c = 1; c < BS; ++c) mx = fmaxf(mx, M[t][c]);
        float s = 0.0f;
        for (int c = 0; c < BS; ++c) { float e = expf(M[t][c] - mx); M[t][c] = e; s += e; }
        float rs = 1.0f / s;
        for (int c = 0; c < BS; ++c) M[t][c] *= rs;
    }
    __syncthreads();
    for (int it = 0; it < 5; ++it) {
        if (t < BS) {
            float s = 0.0f;
            for (int c = 0; c < BS; ++c) s += M[t][c];
            float rs = 1.0f / s;
            for (int c = 0; c < BS; ++c) M[t][c] *= rs;
        }
        __syncthreads();
        if (t < BS) {
            float s = 0.0f;
            for (int r = 0; r < BS; ++r) s += M[r][t];
            float rs = 1.0f / s;
            for (int r = 0; r < BS; ++r) M[r][t] *= rs;
        }
        __syncthreads();
    }

    int pA = 0, pB = 0;   // row (1-based) assigned to cols t+1 / t+65; 0 = free

    if (t >= 64) {
        // ---- waves1-3: zero the 128-row output stripe (hidden under LAP) ----
        const int l = t - 64;   // 0..191
        float4 z = make_float4(0.f, 0.f, 0.f, 0.f);
        float4* o4 = reinterpret_cast<float4*>(out + (size_t)b * BS * GSZ);
        for (int k = l; k < BS * GSZ / 4; k += 192) o4[k] = z;
    } else {
        // ---- wave0: exact LAP on cost = -P, all state in registers ----
        const int jAcol = t + 1, jBcol = t + 65;
        double uA = 0.0, uB = 0.0, vA, vB;

        // column reduction seed: v[j] = min_i cost = -(max_i P); greedy assign
        {
            float cmA = Mf[t];      int raA = 0;
            float cmB = Mf[t + 64]; int raB = 0;
            for (int r = 1; r < BS; ++r) {
                float xA = Mf[r * (BS + 1) + t];
                if (xA > cmA) { cmA = xA; raA = r; }
                float xB = Mf[r * (BS + 1) + t + 64];
                if (xB > cmB) { cmB = xB; raB = r; }
            }
            vA = -(double)cmA; vB = -(double)cmB;
            rowasg[t] = 0x7FFFFFFF; rowasg[t + 64] = 0x7FFFFFFF;
            __threadfence_block();
            atomicMin(&rowasg[raA], jAcol);
            atomicMin(&rowasg[raB], jBcol);
            __threadfence_block();
            pA = (rowasg[raA] == jAcol) ? raA + 1 : 0;
            pB = (rowasg[raB] == jBcol) ? raB + 1 : 0;
        }

        // unassigned-row masks (rows 1..64 in un0, 65..128 in un1)
        unsigned long long un0 = __ballot(rowasg[t]      == 0x7FFFFFFF);
        unsigned long long un1 = __ballot(rowasg[t + 64] == 0x7FFFFFFF);

        // ---- ARR: augmenting row reduction (lapjv), cap 512 — R8-verified.
        // Keeps v non-increasing (free rows stay feasible at u=0); winners
        // assigned tight (u=u2, v[j1] -= u2-u1). Dijkstra finishes exactly.
        for (int steps = 0; (un0 | un1) && steps < 512; ++steps) {
            int i;
            if (un0) i = __builtin_ctzll(un0) + 1;
            else     i = __builtin_ctzll(un1) + 65;

            double dA = -(double)Mf[(i - 1) * (BS + 1) + t]      - vA;
            double dB = -(double)Mf[(i - 1) * (BS + 1) + t + 64] - vB;
            unsigned long long kA = pkeyc(dA, jAcol), kB = pkeyc(dB, jBcol);

            unsigned long long k1 = wave_min_key(kA < kB ? kA : kB);
            const int  j1  = (int)(k1 & 0xFFull);
            const int  sl1 = (j1 - 1) & 63;
            const bool h1  = j1 > 64;
            double u1 = keyc_val(k1);               // value from key bits

            unsigned long long kA2 = (jAcol == j1) ? ~0ull : kA;
            unsigned long long kB2 = (jBcol == j1) ? ~0ull : kB;
            unsigned long long k2 = wave_min_key(kA2 < kB2 ? kA2 : kB2);
            double u2 = keyc_val(k2);               // value from key bits

            int i1 = rl32(h1 ? pB : pA, sl1);   // previous owner of j1 (0 = none)

            if (t == sl1) {
                if (h1) { pB = i; uB = u2; if (u1 < u2) vB -= (u2 - u1); }
                else    { pA = i; uA = u2; if (u1 < u2) vA -= (u2 - u1); }
            }
            if (i <= 64) un0 &= ~(1ull << (i - 1)); else un1 &= ~(1ull << (i - 65));
            if (i1 > 0) {
                if (i1 <= 64) un0 |= 1ull << (i1 - 1); else un1 |= 1ull << (i1 - 65);
            }
        }

        // ---- single-source Dijkstra phases (R4-verified recursion; pj and
        // value both ride in the key) ----
        while (un0 | un1) {
            int i;
            if (un0) { int r = __builtin_ctzll(un0); un0 &= un0 - 1; i = r + 1; }
            else     { int r = __builtin_ctzll(un1); un1 &= un1 - 1; i = r + 65; }

            bool usedA = false, usedB = false;
            double mA = 1e18, mB = 1e18, SUM = 0.0;   // stored m = true_minv + SUM
            unsigned long long keyA = ~0ull, keyB = ~0ull;
            int wayA = 0, wayB = 0;
            int i0 = i, j0 = 0;
            double ui0 = 0.0;                          // free row: u = 0

            for (int guard = 0; guard <= BS + 2; ++guard) {
                // scan row i0 against this lane's two columns
                float cAv = Mf[(i0 - 1) * (BS + 1) + t];
                float cBv = Mf[(i0 - 1) * (BS + 1) + t + 64];
                if (!usedA) {
                    double nd = (-(double)cAv - ui0 - vA) + SUM;
                    if (nd < mA) { mA = nd; wayA = j0; keyA = pkey16(nd, pA, jAcol); }
                }
                if (!usedB) {
                    double nd = (-(double)cBv - ui0 - vB) + SUM;
                    if (nd < mB) { mB = nd; wayB = j0; keyB = pkey16(nd, pB, jBcol); }
                }
                unsigned long long kw = wave_min_key(keyA < keyB ? keyA : keyB);
                if (kw == ~0ull) break;                  // safety: fail visibly
                const int  j1 = (int)(kw & 0xFFull);
                const int  pj = (int)((kw >> 8) & 0xFFull);
                const int  sl = (j1 - 1) & 63;
                const bool hb = j1 > 64;

                double m_win = key16_val(kw);            // value from key bits
                double delta = m_win - SUM;
                SUM = m_win;
                if (usedA) { uA += delta; vA -= delta; }
                if (usedB) { uB += delta; vB -= delta; }

                j0 = j1;
                if (pj == 0) break;                      // free column: augment
                ui0 = rl64(hb ? uB : uA, sl);            // owner u (pre-mark)
                i0 = pj;
                if (t == sl) { if (hb) { usedB = true; keyB = ~0ull; }
                               else    { usedA = true; keyA = ~0ull; } }
            }

            // augment along way-chain; duals u travel with their rows
            int jc = j0;
            for (int guard = 0; guard <= BS + 2; ++guard) {
                const int  slc = (jc - 1) & 63;
                const bool hc  = jc > 64;
                int jp = rl32(hc ? wayB : wayA, slc);
                int nprow; double nu;
                if (jp == 0) { nprow = i; nu = SUM; }    // start row: u was 0
                else {
                    const int  slp = (jp - 1) & 63;
                    const bool hp  = jp > 64;
                    nprow = rl32(hp ? pB : pA, slp);
                    nu    = rl64(hp ? uB : uA, slp);
                }
                if (!hc) { if (t == slc) { pA = nprow; uA = nu; } }
                else     { if (t == slc) { pB = nprow; uB = nu; } }
                if (jp == 0) break;
                jc = jp;
            }
        }
    }

    __syncthreads();   // stripe fully zeroed, assignment final

    if (t < 64) {
        const size_t base = (size_t)b * BS;
        if (pA >= 1) out[(base + (size_t)(pA - 1)) * GSZ + base + t]      = 1.0f;
        if (pB >= 1) out[(base + (size_t)(pB - 1)) * GSZ + base + t + 64] = 1.0f;
    }
}

extern "C" void kernel_launch(void* const* d_in, const int* in_sizes, int n_in,
                              void* d_out, int out_size, void* d_ws, size_t ws_size,
                              hipStream_t stream) {
    const float* w     = (const float*)d_in[0];
    const float* scale = (const float*)d_in[1];
    float* out = (float*)d_out;
    k_fused<<<NBLK, 256, 0, stream>>>(w, scale, out);
}

// Round 11
// 715.393 us; speedup vs baseline: 1.3867x; 1.0464x over previous
//
#include <hip/hip_runtime.h>
#include <hip/hip_bf16.h>

#define NBLK 64
#define BS   128
#define GSZ  8192   // NBLK * BS

// ---------- wave-uniform register fetch helpers (lane index must be uniform) ----------
__device__ __forceinline__ int rl32(int v, int sl) {
    return __builtin_amdgcn_readlane(v, sl);
}
__device__ __forceinline__ double rl64(double v, int sl) {
    union { double d; unsigned u[2]; } a; a.d = v;
    unsigned lo = (unsigned)__builtin_amdgcn_readlane((int)a.u[0], sl);
    unsigned hi = (unsigned)__builtin_amdgcn_readlane((int)a.u[1], sl);
    union { unsigned u[2]; double d; } r; r.u[0] = lo; r.u[1] = hi;
    return r.d;
}
// key: value bits [63:16] | owner-row pj [15:8] | col [7:0]. The winning
// column's owner, its col, and its value all decode from the key after the
// wave-min — no dependent readlane. 16-bit truncation perturbs pop order and
// (via key16_val, applied consistently) the duals by < 2^-36 relative — far
// below optimum margins (validated R8/R10, absmax 0).
__device__ __forceinline__ unsigned long long pkey16(double m, int pj, int col) {
    union { double d; unsigned long long u; } a; a.d = m;
    unsigned long long x = a.u;
    x = (x >> 63) ? ~x : (x | 0x8000000000000000ull);
    return (x & ~0xFFFFull) | ((unsigned long long)(unsigned)pj << 8)
                            | (unsigned long long)(unsigned)col;
}
// value extraction from key bits (local VALU, no cross-lane op).
__device__ __forceinline__ double key16_val(unsigned long long k) {
    unsigned long long x = k & ~0xFFFFull;
    x = (x & 0x8000000000000000ull) ? (x & 0x7FFFFFFFFFFFFFFFull) : ~x;
    union { unsigned long long u; double d; } r; r.u = x;
    return r.d;
}

// Branchless wave64 min of a 64-bit key via DPP (rocPRIM movement pattern:
// row_shr 1/2/4/8 then row_bcast 15/31), u64 compare + dual cndmask per step.
// bound_ctrl=false / row_mask-excluded lanes keep their own value (self-min).
// Result valid in lane 63; returned wave-uniform via 2 readlanes.
__device__ __forceinline__ unsigned long long wave_min_key64(unsigned long long k) {
    unsigned lo = (unsigned)k, hi = (unsigned)(k >> 32);
#define WMK_STEP(ctrl, rmask)                                                           \
    {                                                                                   \
        unsigned nlo = (unsigned)__builtin_amdgcn_update_dpp((int)lo, (int)lo, ctrl, rmask, 0xf, false); \
        unsigned nhi = (unsigned)__builtin_amdgcn_update_dpp((int)hi, (int)hi, ctrl, rmask, 0xf, false); \
        unsigned long long ny  = ((unsigned long long)nhi << 32) | nlo;                 \
        unsigned long long cur = ((unsigned long long)hi  << 32) | lo;                  \
        if (ny < cur) { lo = nlo; hi = nhi; }                                           \
    }
    WMK_STEP(0x111, 0xf)   // row_shr:1
    WMK_STEP(0x112, 0xf)   // row_shr:2
    WMK_STEP(0x114, 0xf)   // row_shr:4
    WMK_STEP(0x118, 0xf)   // row_shr:8
    WMK_STEP(0x142, 0xa)   // row_bcast:15
    WMK_STEP(0x143, 0xc)   // row_bcast:31
#undef WMK_STEP
    unsigned mlo = (unsigned)__builtin_amdgcn_readlane((int)lo, 63);
    unsigned mhi = (unsigned)__builtin_amdgcn_readlane((int)hi, 63);
    return ((unsigned long long)mhi << 32) | mlo;
}

// ---------------------------------------------------------------------------
// Fused kernel (256 thr): sinkhorn (first 128 thr) -> { wave0: col-reduction
// seed + sequential ARR-512 + register-JV Dijkstra (key-only compare),
// waves1-3: zero-fill the 128x8192 stripe } -> scatter ones.
// ---------------------------------------------------------------------------
__global__ __launch_bounds__(256) void k_fused(const float* __restrict__ w,
                                               const float* __restrict__ scale_p,
                                               float* __restrict__ out) {
    __shared__ float M[BS][BS + 1];   // [128][129] f32: conflict-free rows+cols
    __shared__ int   rowasg[BS];
    float* Mf = &M[0][0];

    const int b = blockIdx.x;
    const int t = threadIdx.x;
    const float scale = *scale_p;

    // ---- sinkhorn: P = sinkhorn(softmax(clamp(w*scale,-1,1)/3)) ----
    if (t < BS) {
        for (int r = 0; r < BS; ++r) {
            float x = w[((size_t)b * BS + r) * BS + t] * scale;
            x = fminf(fmaxf(x, -1.0f), 1.0f);
            M[r][t] = x / 3.0f;
        }
    }
    __syncthreads();
    if (t < BS) {   // softmax along rows (thread t owns row t)
        float mx = M[t][0];
        for (int c = 1; c < BS; ++c) mx = fmaxf(mx, M[t][c]);
        float s = 0.0f;
        for (int c = 0; c < BS; ++c) { float e = expf(M[t][c] - mx); M[t][c] = e; s += e; }
        float rs = 1.0f / s;
        for (int c = 0; c < BS; ++c) M[t][c] *= rs;
    }
    __syncthreads();
    for (int it = 0; it < 5; ++it) {
        if (t < BS) {
            float s = 0.0f;
            for (int c = 0; c < BS; ++c) s += M[t][c];
            float rs = 1.0f / s;
            for (int c = 0; c < BS; ++c) M[t][c] *= rs;
        }
        __syncthreads();
        if (t < BS) {
            float s = 0.0f;
            for (int r = 0; r < BS; ++r) s += M[r][t];
            float rs = 1.0f / s;
            for (int r = 0; r < BS; ++r) M[r][t] *= rs;
        }
        __syncthreads();
    }

    int pA = 0, pB = 0;   // row (1-based) assigned to cols t+1 / t+65; 0 = free

    if (t >= 64) {
        // ---- waves1-3: zero the 128-row output stripe (hidden under LAP) ----
        const int l = t - 64;   // 0..191
        float4 z = make_float4(0.f, 0.f, 0.f, 0.f);
        float4* o4 = reinterpret_cast<float4*>(out + (size_t)b * BS * GSZ);
        for (int k = l; k < BS * GSZ / 4; k += 192) o4[k] = z;
    } else {
        // ---- wave0: exact LAP on cost = -P, all state in registers ----
        const int jAcol = t + 1, jBcol = t + 65;
        double uA = 0.0, uB = 0.0, vA, vB;

        // column reduction seed: v[j] = min_i cost = -(max_i P); greedy assign
        {
            float cmA = Mf[t];      int raA = 0;
            float cmB = Mf[t + 64]; int raB = 0;
            for (int r = 1; r < BS; ++r) {
                float xA = Mf[r * (BS + 1) + t];
                if (xA > cmA) { cmA = xA; raA = r; }
                float xB = Mf[r * (BS + 1) + t + 64];
                if (xB > cmB) { cmB = xB; raB = r; }
            }
            vA = -(double)cmA; vB = -(double)cmB;
            rowasg[t] = 0x7FFFFFFF; rowasg[t + 64] = 0x7FFFFFFF;
            __threadfence_block();
            atomicMin(&rowasg[raA], jAcol);
            atomicMin(&rowasg[raB], jBcol);
            __threadfence_block();
            pA = (rowasg[raA] == jAcol) ? raA + 1 : 0;
            pB = (rowasg[raB] == jBcol) ? raB + 1 : 0;
        }

        // unassigned-row masks (rows 1..64 in un0, 65..128 in un1)
        unsigned long long un0 = __ballot(rowasg[t]      == 0x7FFFFFFF);
        unsigned long long un1 = __ballot(rowasg[t + 64] == 0x7FFFFFFF);

        // ---- ARR: augmenting row reduction (lapjv), cap 512 — R8-verified
        // algebra; owner i1 and values u1/u2 now decode from key bits.
        for (int steps = 0; (un0 | un1) && steps < 512; ++steps) {
            int i;
            if (un0) i = __builtin_ctzll(un0) + 1;
            else     i = __builtin_ctzll(un1) + 65;

            double dA = -(double)Mf[(i - 1) * (BS + 1) + t]      - vA;
            double dB = -(double)Mf[(i - 1) * (BS + 1) + t + 64] - vB;
            unsigned long long kA = pkey16(dA, pA, jAcol), kB = pkey16(dB, pB, jBcol);

            unsigned long long k1 = wave_min_key64(kA < kB ? kA : kB);
            const int  j1  = (int)(k1 & 0xFFull);
            const int  i1  = (int)((k1 >> 8) & 0xFFull);   // previous owner (0 = none)
            const int  sl1 = (j1 - 1) & 63;
            const bool h1  = j1 > 64;
            double u1 = key16_val(k1);

            unsigned long long kA2 = (jAcol == j1) ? ~0ull : kA;
            unsigned long long kB2 = (jBcol == j1) ? ~0ull : kB;
            unsigned long long k2 = wave_min_key64(kA2 < kB2 ? kA2 : kB2);
            double u2 = key16_val(k2);

            if (t == sl1) {
                if (h1) { pB = i; uB = u2; if (u1 < u2) vB -= (u2 - u1); }
                else    { pA = i; uA = u2; if (u1 < u2) vA -= (u2 - u1); }
            }
            if (i <= 64) un0 &= ~(1ull << (i - 1)); else un1 &= ~(1ull << (i - 65));
            if (i1 > 0) {
                if (i1 <= 64) un0 |= 1ull << (i1 - 1); else un1 |= 1ull << (i1 - 65);
            }
        }

        // ---- single-source Dijkstra phases (R4-verified recursion; key-only
        // compare, base precompute keeps one f64 op after the LDS load) ----
        while (un0 | un1) {
            int i;
            if (un0) { int r = __builtin_ctzll(un0); un0 &= un0 - 1; i = r + 1; }
            else     { int r = __builtin_ctzll(un1); un1 &= un1 - 1; i = r + 65; }

            bool usedA = false, usedB = false;
            unsigned long long keyA = ~0ull, keyB = ~0ull;   // value(+SUM)|pj|col
            int wayA = 0, wayB = 0;
            int i0 = i, j0 = 0;
            double ui0 = 0.0, SUM = 0.0;               // free row: u = 0

            for (int guard = 0; guard <= BS + 2; ++guard) {
                // scan row i0 against this lane's two columns
                float cAv = Mf[(i0 - 1) * (BS + 1) + t];
                float cBv = Mf[(i0 - 1) * (BS + 1) + t + 64];
                double baseA = SUM - ui0 - vA;          // overlaps ds_read latency
                double baseB = SUM - ui0 - vB;
                if (!usedA) {
                    unsigned long long nk = pkey16(baseA - (double)cAv, pA, jAcol);
                    if (nk < keyA) { keyA = nk; wayA = j0; }
                }
                if (!usedB) {
                    unsigned long long nk = pkey16(baseB - (double)cBv, pB, jBcol);
                    if (nk < keyB) { keyB = nk; wayB = j0; }
                }
                unsigned long long kw = wave_min_key64(keyA < keyB ? keyA : keyB);
                if (kw == ~0ull) break;                  // safety: fail visibly
                const int  j1 = (int)(kw & 0xFFull);
                const int  pj = (int)((kw >> 8) & 0xFFull);
                const int  sl = (j1 - 1) & 63;
                const bool hb = j1 > 64;

                double m_win = key16_val(kw);            // value from key bits
                double delta = m_win - SUM;
                SUM = m_win;
                if (usedA) { uA += delta; vA -= delta; }
                if (usedB) { uB += delta; vB -= delta; }

                j0 = j1;
                if (pj == 0) break;                      // free column: augment
                ui0 = rl64(hb ? uB : uA, sl);            // owner u (pre-mark)
                i0 = pj;
                if (t == sl) { if (hb) { usedB = true; keyB = ~0ull; }
                               else    { usedA = true; keyA = ~0ull; } }
            }

            // augment along way-chain; duals u travel with their rows
            int jc = j0;
            for (int guard = 0; guard <= BS + 2; ++guard) {
                const int  slc = (jc - 1) & 63;
                const bool hc  = jc > 64;
                int jp = rl32(hc ? wayB : wayA, slc);
                int nprow; double nu;
                if (jp == 0) { nprow = i; nu = SUM; }    // start row: u was 0
                else {
                    const int  slp = (jp - 1) & 63;
                    const bool hp  = jp > 64;
                    nprow = rl32(hp ? pB : pA, slp);
                    nu    = rl64(hp ? uB : uA, slp);
                }
                if (!hc) { if (t == slc) { pA = nprow; uA = nu; } }
                else     { if (t == slc) { pB = nprow; uB = nu; } }
                if (jp == 0) break;
                jc = jp;
            }
        }
    }

    __syncthreads();   // stripe fully zeroed, assignment final

    if (t < 64) {
        const size_t base = (size_t)b * BS;
        if (pA >= 1) out[(base + (size_t)(pA - 1)) * GSZ + base + t]      = 1.0f;
        if (pB >= 1) out[(base + (size_t)(pB - 1)) * GSZ + base + t + 64] = 1.0f;
    }
}

extern "C" void kernel_launch(void* const* d_in, const int* in_sizes, int n_in,
                              void* d_out, int out_size, void* d_ws, size_t ws_size,
                              hipStream_t stream) {
    const float* w     = (const float*)d_in[0];
    const float* scale = (const float*)d_in[1];
    float* out = (float*)d_out;
    k_fused<<<NBLK, 256, 0, stream>>>(w, scale, out);
}